// Round 11
// baseline (280.502 us; speedup 1.0000x reference)
//
#include <hip/hip_runtime.h>
#include <math.h>
#include <stdint.h>

#define N 4096
#define S0 256
#define S1 128
#define S2 64

typedef __bf16 bf16;
typedef __attribute__((ext_vector_type(8))) __bf16 bf16x8;
typedef __attribute__((ext_vector_type(4))) __bf16 bf16x4;
typedef __attribute__((ext_vector_type(4))) float f32x4;
typedef unsigned long long u64;

// ---------------- k_prep (R4-proven): chains + V2b + zero + bitmask ----------------
// blocks [0,512):     chain1: W/Wt = (U0@U1)@U2 fp32; U0 negsq -> ls5[bid]
// blocks [512,1024):  chain2: hnb = l2norm(elu(V2^T@fc1^T+b1)@fc2^T+b2)
// blocks [1024,1088): V2b = bf16(V2); V2 negsq -> ls5[512+nb]
// block 1088:         zero accumulators; U1+U2 negsq -> ls5[576]
// blocks [1089,3137): sim>0.9 ballot bitmask, 2 rows/block

__global__ __launch_bounds__(128) void k_prep(const float* __restrict__ U0,
                                              const float* __restrict__ U1,
                                              const float* __restrict__ U2,
                                              const float* __restrict__ V2,
                                              const float* __restrict__ fc1_w,
                                              const float* __restrict__ fc1_b,
                                              const float* __restrict__ fc2_w,
                                              const float* __restrict__ fc2_b,
                                              float* __restrict__ W,
                                              float* __restrict__ Wt,
                                              bf16* __restrict__ V2b,
                                              bf16* __restrict__ hnb,
                                              float* __restrict__ accz,
                                              float* __restrict__ ls5,
                                              const float* __restrict__ sim,
                                              u64* __restrict__ mask) {
    __shared__ __align__(16) char pb[12416];
    int bid = blockIdx.x;
    int tid = threadIdx.x;
    int lane = tid & 63, wv = tid >> 6;

    if (bid < 512) {
        // ---- chain1: 8 rows, 128 threads ----
        float (*u0s)[S0]      = (float(*)[S0])pb;                    // 8192 B (dead after step1)
        float (*ts)[S1 + 4]   = (float(*)[S1 + 4])(pb + 8192);       // 4224 B
        int i0 = bid * 8;
        float ns = 0.f;

        for (int t = tid; t < 8 * S0; t += 128) {
            float x = U0[(i0 + (t >> 8)) * S0 + (t & 255)];
            u0s[t >> 8][t & 255] = x;
            if (x < 0.f) ns += x * x;
        }
        __syncthreads();
        {
            int j = tid;
            float acc[8] = {};
#pragma unroll 8
            for (int k = 0; k < S0; ++k) {
                float u1 = U1[k * S1 + j];
#pragma unroll
                for (int r = 0; r < 8; ++r) acc[r] += u0s[r][k] * u1;
            }
            for (int r = 0; r < 8; ++r) ts[r][j] = acc[r];
        }
        __syncthreads();
        {
            int j = tid & 63, h = tid >> 6;
            float acc2[4] = {};
#pragma unroll 8
            for (int k = 0; k < S1; ++k) {
                float u2 = U2[k * S2 + j];
#pragma unroll
                for (int r = 0; r < 4; ++r) acc2[r] += ts[h * 4 + r][k] * u2;
            }
            for (int r = 0; r < 4; ++r) {
                int i = i0 + h * 4 + r;
                W[i * S2 + j] = acc2[r];
                Wt[(size_t)j * N + i] = acc2[r];
            }
        }
        // U0 negsq partial
        {
            for (int off = 32; off; off >>= 1) ns += __shfl_down(ns, off, 64);
            __syncthreads();
            float* nsr = (float*)pb;
            if (lane == 0) nsr[wv] = ns;
            __syncthreads();
            if (tid == 0) ls5[bid] = nsr[0] + nsr[1];
        }
    } else if (bid < 1024) {
        // ---- chain2: 8 rows, 128 threads ----
        float (*vs)[S2]       = (float(*)[S2])pb;                    // 2048 B
        float (*hs)[S1 + 4]   = (float(*)[S1 + 4])(pb + 2048);       // 4224 B
        float (*red)[8]       = (float(*)[8])(pb + 6272);            // 64 B
        float *norms          = (float*)(pb + 6336);                 // 32 B
        int i0 = (bid - 512) * 8;

        for (int t = tid; t < 8 * S2; t += 128) {
            int r = t & 7, k = t >> 3;
            vs[r][k] = V2[k * N + i0 + r];
        }
        __syncthreads();
        {
            int j = tid;
            float b = fc1_b[j];
            float acc[8];
#pragma unroll
            for (int r = 0; r < 8; ++r) acc[r] = b;
#pragma unroll 4
            for (int kk = 0; kk < S2; kk += 4) {
                float4 w4 = *(const float4*)(fc1_w + j * S2 + kk);
#pragma unroll
                for (int r = 0; r < 8; ++r) {
                    float4 v4 = *(const float4*)(&vs[r][kk]);
                    acc[r] += v4.x * w4.x + v4.y * w4.y + v4.z * w4.z + v4.w * w4.w;
                }
            }
            for (int r = 0; r < 8; ++r) {
                float x = acc[r];
                hs[r][j] = x > 0.f ? x : (expf(x) - 1.f);
            }
        }
        __syncthreads();
        {
            int j = tid;
            float b0 = fc2_b[j], b1 = fc2_b[j + 128];
            float a0[8], a1[8];
#pragma unroll
            for (int r = 0; r < 8; ++r) { a0[r] = b0; a1[r] = b1; }
#pragma unroll 4
            for (int kk = 0; kk < S1; kk += 4) {
                float4 w0 = *(const float4*)(fc2_w + j * S1 + kk);
                float4 w1 = *(const float4*)(fc2_w + (j + 128) * S1 + kk);
#pragma unroll
                for (int r = 0; r < 8; ++r) {
                    float4 h4 = *(const float4*)(&hs[r][kk]);
                    a0[r] += h4.x * w0.x + h4.y * w0.y + h4.z * w0.z + h4.w * w0.w;
                    a1[r] += h4.x * w1.x + h4.y * w1.y + h4.z * w1.z + h4.w * w1.w;
                }
            }
#pragma unroll
            for (int r = 0; r < 8; ++r) {
                float v = a0[r] * a0[r] + a1[r] * a1[r];
                for (int off = 32; off; off >>= 1) v += __shfl_down(v, off, 64);
                if (lane == 0) red[wv][r] = v;
            }
            __syncthreads();
            if (tid < 8) norms[tid] = fmaxf(sqrtf(red[0][tid] + red[1][tid]), 1e-12f);
            __syncthreads();
            for (int r = 0; r < 8; ++r) {
                float inv = 1.f / norms[r];
                hnb[(i0 + r) * S0 + j] = (bf16)(a0[r] * inv);
                hnb[(i0 + r) * S0 + j + 128] = (bf16)(a1[r] * inv);
            }
        }
    } else if (bid < 1088) {
        // ---- V2 -> bf16 + V2 negsq ----
        int nb = bid - 1024;
        float ns = 0.f;
#pragma unroll
        for (int it = 0; it < 8; ++it) {
            int fi = nb * 1024 + it * 128 + tid;
            float4 x = *(const float4*)(V2 + (size_t)fi * 4);
            bf16x4 v = {(bf16)x.x, (bf16)x.y, (bf16)x.z, (bf16)x.w};
            *(bf16x4*)(V2b + (size_t)fi * 4) = v;
            if (x.x < 0.f) ns += x.x * x.x;
            if (x.y < 0.f) ns += x.y * x.y;
            if (x.z < 0.f) ns += x.z * x.z;
            if (x.w < 0.f) ns += x.w * x.w;
        }
        for (int off = 32; off; off >>= 1) ns += __shfl_down(ns, off, 64);
        float* nsr = (float*)pb;
        if (lane == 0) nsr[wv] = ns;
        __syncthreads();
        if (tid == 0) ls5[512 + nb] = nsr[0] + nsr[1];
    } else if (bid == 1088) {
        // ---- zero accumulators + U1/U2 negsq ----
        float ns = 0.f;
        for (int t = tid; t < (S0 * S1 + S1 * S2) / 4; t += 128) {
            float4 x = (t < S0 * S1 / 4) ? ((const float4*)U1)[t]
                                         : ((const float4*)U2)[t - S0 * S1 / 4];
            if (x.x < 0.f) ns += x.x * x.x;
            if (x.y < 0.f) ns += x.y * x.y;
            if (x.z < 0.f) ns += x.z * x.z;
            if (x.w < 0.f) ns += x.w * x.w;
        }
        for (int t = tid; t < 4 * N + 8; t += 128) accz[t] = 0.f;
        for (int off = 32; off; off >>= 1) ns += __shfl_down(ns, off, 64);
        float* nsr = (float*)pb;
        if (lane == 0) nsr[wv] = ns;
        __syncthreads();
        if (tid == 0) ls5[576] = nsr[0] + nsr[1];
    } else {
        // ---- sim>0.9 ballot bitmask, 2 rows/block ----
        int row = (bid - 1089) * 2 + wv;
        const float* base = sim + (size_t)row * N + lane * 4;
#pragma unroll
        for (int half = 0; half < 2; ++half) {
            float4 x[8];
#pragma unroll
            for (int it = 0; it < 8; ++it)
                x[it] = *(const float4*)(base + (half * 8 + it) * 256);
#pragma unroll
            for (int it = 0; it < 8; ++it) {
                u64 b0 = __ballot(x[it].x > 0.9f);
                u64 b1 = __ballot(x[it].y > 0.9f);
                u64 b2 = __ballot(x[it].z > 0.9f);
                u64 b3 = __ballot(x[it].w > 0.9f);
                if (lane < 4) {
                    u64 v = (lane == 0) ? b0 : (lane == 1) ? b1 : (lane == 2) ? b2 : b3;
                    mask[(size_t)row * 64 + (half * 8 + it) * 4 + lane] = v;
                }
            }
        }
    }
}

// ---------------- k_work v2: sim tiles direct-from-L2 (no As/Bs staging) ----------------
// blocks [0,1024):    refl_sim MFMA, fragments loaded straight from hnb (L2-resident 2MB);
//                     LDS only for mask words + per-row reductions (5.2 KB -> high occupancy)
// blocks [1024,1408): pos_idx tail (pos2/pos3)
// blocks [1408,1920): loss1G MFMA (verbatim)
// blocks [1920,2440): gram pairs upper triangle (verbatim)

__global__ __launch_bounds__(256) void k_work(const bf16* __restrict__ hnb,
                                              const u64* __restrict__ mask,
                                              float* __restrict__ rowsum,
                                              float* __restrict__ pos4,
                                              const int* __restrict__ cIdx,
                                              const int* __restrict__ nIdx,
                                              float* __restrict__ pos2,
                                              float* __restrict__ pos3,
                                              const float* __restrict__ V2,
                                              const float* __restrict__ A,
                                              const bf16* __restrict__ V2b,
                                              const float* __restrict__ W,
                                              const float* __restrict__ Wt,
                                              double* __restrict__ lacc,
                                              double* __restrict__ pairsum) {
    __shared__ __align__(16) u64 mwords[512];        // 4096 B
    __shared__ float rs_l[128], ps_l[128];           // 1024 B
    int bid = blockIdx.x;
    int tid = threadIdx.x;
    int lane = tid & 63, w = tid >> 6;

    if (bid >= 1024 && bid < 1408) {
        // ---- pos_idx tail ----
        int g = (bid - 1024) * 256 + tid;
        if (g >= N * 24) return;
        int i = g / 24, s = g % 24;
        const int* idx;
        int kk;
        float* dst;
        if (s < 8) { idx = cIdx + i * 8; kk = s; dst = pos2; }
        else       { idx = nIdx + i * 16; kk = s - 8; dst = pos3; }
        int t = idx[kk];
        for (int k = 0; k < kk; ++k)
            if (idx[k] == t) return;  // mask is a set: duplicates count once
        const bf16* a = hnb + i * S0;
        const bf16* b = hnb + t * S0;
        float dsum = 0.f;
        for (int k = 0; k < S0; k += 8) {
            bf16x8 av = *(const bf16x8*)(a + k);
            bf16x8 bv = *(const bf16x8*)(b + k);
#pragma unroll
            for (int u = 0; u < 8; ++u) dsum += (float)av[u] * (float)bv[u];
        }
        atomicAdd(dst + i, __expf(2.f * dsum));
        return;
    }

    if (bid >= 1408 && bid < 1920) {
        // ---- loss1G: direct-load MFMA ----
        float* reds = rs_l;               // alias
        float* redc = ps_l;               // alias
        int b = bid - 1408;
        int split = b >> 5, rb = b & 31;
        int i0 = rb * 128, k0 = split * 256;
        int q = lane >> 4, l15 = lane & 15;

        f32x4 zero = {0.f, 0.f, 0.f, 0.f};
        f32x4 acc[2][4];
#pragma unroll
        for (int a = 0; a < 2; ++a)
#pragma unroll
            for (int c = 0; c < 4; ++c) acc[a][c] = zero;
        float a2 = 0.f;

        const float* arow = A + (size_t)(i0 + w * 32 + l15) * N + q * 8;
        for (int ch = 0; ch < 8; ++ch) {
            int jb = k0 + ch * 32;
            float4 xa0 = *(const float4*)(arow + jb);
            float4 xa1 = *(const float4*)(arow + jb + 4);
            float4 xb0 = *(const float4*)(arow + (size_t)16 * N + jb);
            float4 xb1 = *(const float4*)(arow + (size_t)16 * N + jb + 4);
            bf16x8 bfr[4];
#pragma unroll
            for (int tb = 0; tb < 4; ++tb)
                bfr[tb] = *(const bf16x8*)(V2b + (size_t)(tb * 16 + l15) * N + jb + q * 8);
            a2 += xa0.x * xa0.x + xa0.y * xa0.y + xa0.z * xa0.z + xa0.w * xa0.w;
            a2 += xa1.x * xa1.x + xa1.y * xa1.y + xa1.z * xa1.z + xa1.w * xa1.w;
            a2 += xb0.x * xb0.x + xb0.y * xb0.y + xb0.z * xb0.z + xb0.w * xb0.w;
            a2 += xb1.x * xb1.x + xb1.y * xb1.y + xb1.z * xb1.z + xb1.w * xb1.w;
            bf16x8 af0 = {(bf16)xa0.x, (bf16)xa0.y, (bf16)xa0.z, (bf16)xa0.w,
                          (bf16)xa1.x, (bf16)xa1.y, (bf16)xa1.z, (bf16)xa1.w};
            bf16x8 af1 = {(bf16)xb0.x, (bf16)xb0.y, (bf16)xb0.z, (bf16)xb0.w,
                          (bf16)xb1.x, (bf16)xb1.y, (bf16)xb1.z, (bf16)xb1.w};
#pragma unroll
            for (int tb = 0; tb < 4; ++tb) {
                acc[0][tb] = __builtin_amdgcn_mfma_f32_16x16x32_bf16(af0, bfr[tb], acc[0][tb], 0, 0, 0);
                acc[1][tb] = __builtin_amdgcn_mfma_f32_16x16x32_bf16(af1, bfr[tb], acc[1][tb], 0, 0, 0);
            }
        }
        // cross partial: sum W[i][col] * G[i][col]
        float cr = 0.f;
#pragma unroll
        for (int ta = 0; ta < 2; ++ta)
#pragma unroll
            for (int v = 0; v < 4; ++v) {
                int i = i0 + w * 32 + ta * 16 + q * 4 + v;
                const float* wrow = W + (size_t)i * S2 + l15;
#pragma unroll
                for (int tb = 0; tb < 4; ++tb)
                    cr += wrow[tb * 16] * acc[ta][tb][v];
            }
        for (int off = 32; off; off >>= 1) {
            cr += __shfl_down(cr, off, 64);
            a2 += __shfl_down(a2, off, 64);
        }
        if (lane == 0) { reds[w] = a2; redc[w] = cr; }
        __syncthreads();
        if (tid == 0) {
            atomicAdd(lacc + 0, (double)(reds[0] + reds[1] + reds[2] + reds[3]));
            atomicAdd(lacc + 2, (double)(redc[0] + redc[1] + redc[2] + redc[3]));
        }
        return;
    }

    if (bid >= 1920) {
        // ---- gram pairs, upper triangle: one wave per (k<=l) ----
        double* gred = (double*)mwords;   // alias
        int p = (bid - 1920) * 4 + w;
        int kk = (int)((129.0 - sqrt(16641.0 - 8.0 * (double)p)) * 0.5);
        while ((kk + 1) * (129 - (kk + 1)) / 2 <= p) ++kk;
        while (kk * (129 - kk) / 2 > p) --kk;
        int ll = kk + (p - kk * (129 - kk) / 2);
        const float* wk = Wt + (size_t)kk * N;
        const float* wl = Wt + (size_t)ll * N;
        const float* vk = V2 + (size_t)kk * N;
        const float* vl = V2 + (size_t)ll * N;
        float s1 = 0.f, s2 = 0.f;
        for (int it = 0; it < 16; ++it) {
            int j = it * 256 + lane * 4;
            float4 a1 = *(const float4*)(wk + j);
            float4 b1 = *(const float4*)(wl + j);
            float4 a2v = *(const float4*)(vk + j);
            float4 b2v = *(const float4*)(vl + j);
            s1 += a1.x * b1.x + a1.y * b1.y + a1.z * b1.z + a1.w * b1.w;
            s2 += a2v.x * b2v.x + a2v.y * b2v.y + a2v.z * b2v.z + a2v.w * b2v.w;
        }
        for (int off = 32; off; off >>= 1) {
            s1 += __shfl_down(s1, off, 64);
            s2 += __shfl_down(s2, off, 64);
        }
        if (lane == 0) gred[w] = (double)s1 * (double)s2 * ((kk == ll) ? 1.0 : 2.0);
        __syncthreads();
        if (tid == 0)
            pairsum[bid - 1920] = gred[0] + gred[1] + gred[2] + gred[3];
        return;
    }

    // ---- refl_sim tile (bid < 1024): fragments direct from hnb (L2-hot) ----
    int i0 = (bid >> 5) * 128, j0 = (bid & 31) * 128;
    int wm = (w >> 1) * 64, wn = (w & 1) * 64;
    int q = lane >> 4, l15 = lane & 15;
    if (tid < 128) { rs_l[tid] = 0.f; ps_l[tid] = 0.f; }

    // stage mask words (independent of MFMA; visibility at the next barrier)
    int stripe = j0 >> 8, half = (j0 >> 7) & 1;
    for (int t = tid; t < 512; t += 256) {
        int li = t >> 2, u = t & 3;
        mwords[t] = mask[(size_t)(i0 + li) * 64 + stripe * 4 + u];
    }

    f32x4 zero = {0.f, 0.f, 0.f, 0.f};
    f32x4 d[4][4];
#pragma unroll
    for (int a = 0; a < 4; ++a)
#pragma unroll
        for (int b = 0; b < 4; ++b) d[a][b] = zero;

    const bf16* abase = hnb + (size_t)(i0 + wm + l15) * S0 + q * 8;
    const bf16* bbase = hnb + (size_t)(j0 + wn + l15) * S0 + q * 8;
    for (int k = 0; k < S0; k += 32) {
        bf16x8 af[4], bfr[4];
#pragma unroll
        for (int ta = 0; ta < 4; ++ta)
            af[ta] = *(const bf16x8*)(abase + (size_t)(ta * 16) * S0 + k);
#pragma unroll
        for (int tb = 0; tb < 4; ++tb)
            bfr[tb] = *(const bf16x8*)(bbase + (size_t)(tb * 16) * S0 + k);
#pragma unroll
        for (int ta = 0; ta < 4; ++ta)
#pragma unroll
            for (int tb = 0; tb < 4; ++tb)
                d[ta][tb] = __builtin_amdgcn_mfma_f32_16x16x32_bf16(af[ta], bfr[tb], d[ta][tb], 0, 0, 0);
    }
    __syncthreads();   // mwords + rs_l/ps_l zeros visible
    int bitbase = half * 32 + (wn >> 2) + (l15 >> 2);
    int uoff = l15 & 3;
#pragma unroll
    for (int ta = 0; ta < 4; ++ta)
#pragma unroll
        for (int v = 0; v < 4; ++v) {
            int li = wm + ta * 16 + q * 4 + v;
            u64 word = mwords[li * 4 + uoff];
            float rs = 0.f, ps = 0.f;
#pragma unroll
            for (int tb = 0; tb < 4; ++tb) {
                float s = __expf(2.f * d[ta][tb][v]);
                rs += s;
                ps += ((word >> (bitbase + tb * 4)) & 1ULL) ? s : 0.f;
            }
#pragma unroll
            for (int m = 1; m < 16; m <<= 1) {
                rs += __shfl_xor(rs, m, 16);
                ps += __shfl_xor(ps, m, 16);
            }
            if (l15 == 0) {
                atomicAdd(&rs_l[li], rs);
                atomicAdd(&ps_l[li], ps);
            }
        }
    __syncthreads();
    if (tid < 128) {
        atomicAdd(&rowsum[i0 + tid], rs_l[tid]);
        atomicAdd(&pos4[i0 + tid], ps_l[tid]);
    }
}

// ---------------- finalize ----------------

__global__ __launch_bounds__(256) void k_final(const float* __restrict__ rowsum,
                                               const float* __restrict__ pos2,
                                               const float* __restrict__ pos3,
                                               const float* __restrict__ pos4,
                                               const double* __restrict__ lacc,
                                               const double* __restrict__ pairsum,
                                               const float* __restrict__ ls5,
                                               float* __restrict__ out) {
    __shared__ double red[5][4];
    int tid = threadIdx.x;
    double l2 = 0, l3 = 0, l4 = 0, sp = 0, l5 = 0;
    for (int i = tid; i < N; i += 256) {
        double rs = (double)rowsum[i];
        float p2 = pos2[i], p3 = pos3[i], p4 = pos4[i];
        if (p2 > 0.f) l2 -= log((double)p2 / rs);
        if (p3 > 0.f) l3 -= log((double)p3 / rs);
        if (p4 > 0.f) l4 -= log((double)p4 / rs);
    }
    for (int i = tid; i < 520; i += 256) sp += pairsum[i];
    for (int i = tid; i < 577; i += 256) l5 += (double)ls5[i];
    int lane = tid & 63, wave = tid >> 6;
    for (int off = 32; off; off >>= 1) {
        l2 += __shfl_down(l2, off, 64);
        l3 += __shfl_down(l3, off, 64);
        l4 += __shfl_down(l4, off, 64);
        sp += __shfl_down(sp, off, 64);
        l5 += __shfl_down(l5, off, 64);
    }
    if (lane == 0) { red[0][wave] = l2; red[1][wave] = l3; red[2][wave] = l4; red[3][wave] = sp; red[4][wave] = l5; }
    __syncthreads();
    if (tid == 0) {
        double L2 = 0, L3 = 0, L4 = 0, SP = 0, L5 = 0;
        for (int w = 0; w < 4; ++w) {
            L2 += red[0][w]; L3 += red[1][w]; L4 += red[2][w]; SP += red[3][w]; L5 += red[4][w];
        }
        L2 /= N; L3 /= N; L4 /= N;
        double L1 = lacc[0] - 2.0 * lacc[2] + SP;   // sumA2 - 2*cross + sumP2
        double total = L1 + 0.1 * (L2 + L3 + L4) + L5;
        out[0] = (float)total;
        out[1] = (float)L1;
        out[2] = (float)L2;
        out[3] = (float)L3;
        out[4] = (float)L4;
        out[5] = (float)L5;
    }
}

extern "C" void kernel_launch(void* const* d_in, const int* in_sizes, int n_in,
                              void* d_out, int out_size, void* d_ws, size_t ws_size,
                              hipStream_t stream) {
    const float* A     = (const float*)d_in[0];
    const float* U0    = (const float*)d_in[1];
    const float* U1    = (const float*)d_in[2];
    const float* U2    = (const float*)d_in[3];
    const float* V2    = (const float*)d_in[4];
    const float* fc1_w = (const float*)d_in[5];
    const float* fc1_b = (const float*)d_in[6];
    const float* fc2_w = (const float*)d_in[7];
    const float* fc2_b = (const float*)d_in[8];
    const float* sim   = (const float*)d_in[9];
    const int* cIdx    = (const int*)d_in[10];
    const int* nIdx    = (const int*)d_in[11];

    float* ws = (float*)d_ws;
    float* rowsum = ws;
    float* pos2 = ws + N;
    float* pos3 = ws + 2 * N;
    float* pos4 = ws + 3 * N;
    double* lacc = (double*)(ws + 4 * N);            // 4 doubles: sumA2, (unused), cross, (unused)
    double* pairsum = lacc + 4;                      // 1024 doubles (520 used)
    u64* mask = (u64*)(pairsum + 1024);              // N*64 words = 2 MB
    bf16* hnb = (bf16*)(mask + (size_t)N * 64);      // 2 MB
    float* W  = (float*)(hnb + (size_t)N * S0);      // N*S2 fp32 = 1 MB
    float* Wt = W + (size_t)N * S2;                  // S2*N fp32 = 1 MB
    bf16* V2b = (bf16*)(Wt + (size_t)S2 * N);        // 0.5 MB
    float* ls5 = (float*)(V2b + (size_t)S2 * N);     // 577 floats

    k_prep<<<3137, 128, 0, stream>>>(U0, U1, U2, V2, fc1_w, fc1_b, fc2_w, fc2_b,
                                     W, Wt, V2b, hnb, ws, ls5, sim, mask);
    k_work<<<2440, 256, 0, stream>>>(hnb, mask, rowsum, pos4, cIdx, nIdx,
                                     pos2, pos3, V2, A, V2b, W, Wt,
                                     lacc, pairsum);
    k_final<<<1, 256, 0, stream>>>(rowsum, pos2, pos3, pos4, lacc, pairsum, ls5,
                                   (float*)d_out);
}

// Round 12
// 255.349 us; speedup vs baseline: 1.0985x; 1.0985x over previous
//
#include <hip/hip_runtime.h>
#include <math.h>
#include <stdint.h>

#define N 4096
#define S0 256
#define S1 128
#define S2 64
#define LDK 72    // sim-tile LDS row stride in bf16 (144 B): conflict-free b128 reads

typedef __bf16 bf16;
typedef __attribute__((ext_vector_type(8))) __bf16 bf16x8;
typedef __attribute__((ext_vector_type(4))) __bf16 bf16x4;
typedef __attribute__((ext_vector_type(4))) float f32x4;
typedef unsigned long long u64;

// ---------------- k_prep (R4-proven): chains + V2b + zero + bitmask ----------------
// blocks [0,512):     chain1: W/Wt = (U0@U1)@U2 fp32; U0 negsq -> ls5[bid]
// blocks [512,1024):  chain2: hnb = l2norm(elu(V2^T@fc1^T+b1)@fc2^T+b2)
// blocks [1024,1088): V2b = bf16(V2); V2 negsq -> ls5[512+nb]
// block 1088:         zero accumulators; U1+U2 negsq -> ls5[576]
// blocks [1089,3137): sim>0.9 ballot bitmask, 2 rows/block

__global__ __launch_bounds__(128) void k_prep(const float* __restrict__ U0,
                                              const float* __restrict__ U1,
                                              const float* __restrict__ U2,
                                              const float* __restrict__ V2,
                                              const float* __restrict__ fc1_w,
                                              const float* __restrict__ fc1_b,
                                              const float* __restrict__ fc2_w,
                                              const float* __restrict__ fc2_b,
                                              float* __restrict__ W,
                                              float* __restrict__ Wt,
                                              bf16* __restrict__ V2b,
                                              bf16* __restrict__ hnb,
                                              float* __restrict__ accz,
                                              float* __restrict__ ls5,
                                              const float* __restrict__ sim,
                                              u64* __restrict__ mask) {
    __shared__ __align__(16) char pb[12416];
    int bid = blockIdx.x;
    int tid = threadIdx.x;
    int lane = tid & 63, wv = tid >> 6;

    if (bid < 512) {
        // ---- chain1: 8 rows, 128 threads ----
        float (*u0s)[S0]      = (float(*)[S0])pb;                    // 8192 B (dead after step1)
        float (*ts)[S1 + 4]   = (float(*)[S1 + 4])(pb + 8192);       // 4224 B
        int i0 = bid * 8;
        float ns = 0.f;

        for (int t = tid; t < 8 * S0; t += 128) {
            float x = U0[(i0 + (t >> 8)) * S0 + (t & 255)];
            u0s[t >> 8][t & 255] = x;
            if (x < 0.f) ns += x * x;
        }
        __syncthreads();
        {
            int j = tid;
            float acc[8] = {};
#pragma unroll 8
            for (int k = 0; k < S0; ++k) {
                float u1 = U1[k * S1 + j];
#pragma unroll
                for (int r = 0; r < 8; ++r) acc[r] += u0s[r][k] * u1;
            }
            for (int r = 0; r < 8; ++r) ts[r][j] = acc[r];
        }
        __syncthreads();
        {
            int j = tid & 63, h = tid >> 6;
            float acc2[4] = {};
#pragma unroll 8
            for (int k = 0; k < S1; ++k) {
                float u2 = U2[k * S2 + j];
#pragma unroll
                for (int r = 0; r < 4; ++r) acc2[r] += ts[h * 4 + r][k] * u2;
            }
            for (int r = 0; r < 4; ++r) {
                int i = i0 + h * 4 + r;
                W[i * S2 + j] = acc2[r];
                Wt[(size_t)j * N + i] = acc2[r];
            }
        }
        // U0 negsq partial
        {
            for (int off = 32; off; off >>= 1) ns += __shfl_down(ns, off, 64);
            __syncthreads();
            float* nsr = (float*)pb;
            if (lane == 0) nsr[wv] = ns;
            __syncthreads();
            if (tid == 0) ls5[bid] = nsr[0] + nsr[1];
        }
    } else if (bid < 1024) {
        // ---- chain2: 8 rows, 128 threads ----
        float (*vs)[S2]       = (float(*)[S2])pb;                    // 2048 B
        float (*hs)[S1 + 4]   = (float(*)[S1 + 4])(pb + 2048);       // 4224 B
        float (*red)[8]       = (float(*)[8])(pb + 6272);            // 64 B
        float *norms          = (float*)(pb + 6336);                 // 32 B
        int i0 = (bid - 512) * 8;

        for (int t = tid; t < 8 * S2; t += 128) {
            int r = t & 7, k = t >> 3;
            vs[r][k] = V2[k * N + i0 + r];
        }
        __syncthreads();
        {
            int j = tid;
            float b = fc1_b[j];
            float acc[8];
#pragma unroll
            for (int r = 0; r < 8; ++r) acc[r] = b;
#pragma unroll 4
            for (int kk = 0; kk < S2; kk += 4) {
                float4 w4 = *(const float4*)(fc1_w + j * S2 + kk);
#pragma unroll
                for (int r = 0; r < 8; ++r) {
                    float4 v4 = *(const float4*)(&vs[r][kk]);
                    acc[r] += v4.x * w4.x + v4.y * w4.y + v4.z * w4.z + v4.w * w4.w;
                }
            }
            for (int r = 0; r < 8; ++r) {
                float x = acc[r];
                hs[r][j] = x > 0.f ? x : (expf(x) - 1.f);
            }
        }
        __syncthreads();
        {
            int j = tid;
            float b0 = fc2_b[j], b1 = fc2_b[j + 128];
            float a0[8], a1[8];
#pragma unroll
            for (int r = 0; r < 8; ++r) { a0[r] = b0; a1[r] = b1; }
#pragma unroll 4
            for (int kk = 0; kk < S1; kk += 4) {
                float4 w0 = *(const float4*)(fc2_w + j * S1 + kk);
                float4 w1 = *(const float4*)(fc2_w + (j + 128) * S1 + kk);
#pragma unroll
                for (int r = 0; r < 8; ++r) {
                    float4 h4 = *(const float4*)(&hs[r][kk]);
                    a0[r] += h4.x * w0.x + h4.y * w0.y + h4.z * w0.z + h4.w * w0.w;
                    a1[r] += h4.x * w1.x + h4.y * w1.y + h4.z * w1.z + h4.w * w1.w;
                }
            }
#pragma unroll
            for (int r = 0; r < 8; ++r) {
                float v = a0[r] * a0[r] + a1[r] * a1[r];
                for (int off = 32; off; off >>= 1) v += __shfl_down(v, off, 64);
                if (lane == 0) red[wv][r] = v;
            }
            __syncthreads();
            if (tid < 8) norms[tid] = fmaxf(sqrtf(red[0][tid] + red[1][tid]), 1e-12f);
            __syncthreads();
            for (int r = 0; r < 8; ++r) {
                float inv = 1.f / norms[r];
                hnb[(i0 + r) * S0 + j] = (bf16)(a0[r] * inv);
                hnb[(i0 + r) * S0 + j + 128] = (bf16)(a1[r] * inv);
            }
        }
    } else if (bid < 1088) {
        // ---- V2 -> bf16 + V2 negsq ----
        int nb = bid - 1024;
        float ns = 0.f;
#pragma unroll
        for (int it = 0; it < 8; ++it) {
            int fi = nb * 1024 + it * 128 + tid;
            float4 x = *(const float4*)(V2 + (size_t)fi * 4);
            bf16x4 v = {(bf16)x.x, (bf16)x.y, (bf16)x.z, (bf16)x.w};
            *(bf16x4*)(V2b + (size_t)fi * 4) = v;
            if (x.x < 0.f) ns += x.x * x.x;
            if (x.y < 0.f) ns += x.y * x.y;
            if (x.z < 0.f) ns += x.z * x.z;
            if (x.w < 0.f) ns += x.w * x.w;
        }
        for (int off = 32; off; off >>= 1) ns += __shfl_down(ns, off, 64);
        float* nsr = (float*)pb;
        if (lane == 0) nsr[wv] = ns;
        __syncthreads();
        if (tid == 0) ls5[512 + nb] = nsr[0] + nsr[1];
    } else if (bid == 1088) {
        // ---- zero accumulators + U1/U2 negsq ----
        float ns = 0.f;
        for (int t = tid; t < (S0 * S1 + S1 * S2) / 4; t += 128) {
            float4 x = (t < S0 * S1 / 4) ? ((const float4*)U1)[t]
                                         : ((const float4*)U2)[t - S0 * S1 / 4];
            if (x.x < 0.f) ns += x.x * x.x;
            if (x.y < 0.f) ns += x.y * x.y;
            if (x.z < 0.f) ns += x.z * x.z;
            if (x.w < 0.f) ns += x.w * x.w;
        }
        for (int t = tid; t < 4 * N + 8; t += 128) accz[t] = 0.f;
        for (int off = 32; off; off >>= 1) ns += __shfl_down(ns, off, 64);
        float* nsr = (float*)pb;
        if (lane == 0) nsr[wv] = ns;
        __syncthreads();
        if (tid == 0) ls5[576] = nsr[0] + nsr[1];
    } else {
        // ---- sim>0.9 ballot bitmask, 2 rows/block ----
        int row = (bid - 1089) * 2 + wv;
        const float* base = sim + (size_t)row * N + lane * 4;
#pragma unroll
        for (int half = 0; half < 2; ++half) {
            float4 x[8];
#pragma unroll
            for (int it = 0; it < 8; ++it)
                x[it] = *(const float4*)(base + (half * 8 + it) * 256);
#pragma unroll
            for (int it = 0; it < 8; ++it) {
                u64 b0 = __ballot(x[it].x > 0.9f);
                u64 b1 = __ballot(x[it].y > 0.9f);
                u64 b2 = __ballot(x[it].z > 0.9f);
                u64 b3 = __ballot(x[it].w > 0.9f);
                if (lane < 4) {
                    u64 v = (lane == 0) ? b0 : (lane == 1) ? b1 : (lane == 2) ? b2 : b3;
                    mask[(size_t)row * 64 + (half * 8 + it) * 4 + lane] = v;
                }
            }
        }
    }
}

// ---------------- k_work v3: symmetric sim tiles (upper triangle) + mid segments ----------------
// blocks [0,528):     refl_sim upper-triangle tile (ti<=tj); off-diag tiles also emit the
//                     transposed contributions (column sums + transposed mask bits)
// blocks [528,912):   pos_idx tail (pos2/pos3)
// blocks [912,1424):  loss1G MFMA (R9 verbatim)
// blocks [1424,1944): gram pairs upper triangle (R9 verbatim)

__global__ __launch_bounds__(256) void k_work(const bf16* __restrict__ hnb,
                                              const u64* __restrict__ mask,
                                              float* __restrict__ rowsum,
                                              float* __restrict__ pos4,
                                              const int* __restrict__ cIdx,
                                              const int* __restrict__ nIdx,
                                              float* __restrict__ pos2,
                                              float* __restrict__ pos3,
                                              const float* __restrict__ V2,
                                              const float* __restrict__ A,
                                              const bf16* __restrict__ V2b,
                                              const float* __restrict__ W,
                                              const float* __restrict__ Wt,
                                              double* __restrict__ lacc,
                                              double* __restrict__ pairsum) {
    __shared__ __align__(16) bf16 As[128 * LDK];     // 18432 B; aliased as mwords after MFMA
    __shared__ __align__(16) bf16 Bs[128 * LDK];     // 18432 B; aliased as mwordsT after MFMA
    __shared__ float rs_l[128], ps_l[128];
    __shared__ float rs_c[128], ps_c[128];
    int bid = blockIdx.x;
    int tid = threadIdx.x;
    int lane = tid & 63, w = tid >> 6;

    if (bid >= 528 && bid < 912) {
        // ---- pos_idx tail ----
        int g = (bid - 528) * 256 + tid;
        if (g >= N * 24) return;
        int i = g / 24, s = g % 24;
        const int* idx;
        int kk;
        float* dst;
        if (s < 8) { idx = cIdx + i * 8; kk = s; dst = pos2; }
        else       { idx = nIdx + i * 16; kk = s - 8; dst = pos3; }
        int t = idx[kk];
        for (int k = 0; k < kk; ++k)
            if (idx[k] == t) return;  // mask is a set: duplicates count once
        const bf16* a = hnb + i * S0;
        const bf16* b = hnb + t * S0;
        float dsum = 0.f;
        for (int k = 0; k < S0; k += 8) {
            bf16x8 av = *(const bf16x8*)(a + k);
            bf16x8 bv = *(const bf16x8*)(b + k);
#pragma unroll
            for (int u = 0; u < 8; ++u) dsum += (float)av[u] * (float)bv[u];
        }
        atomicAdd(dst + i, __expf(2.f * dsum));
        return;
    }

    if (bid >= 912 && bid < 1424) {
        // ---- loss1G: direct-load MFMA ----
        float* reds = (float*)As;
        float* redc = reds + 4;
        int b = bid - 912;
        int split = b >> 5, rb = b & 31;
        int i0 = rb * 128, k0 = split * 256;
        int q = lane >> 4, l15 = lane & 15;

        f32x4 zero = {0.f, 0.f, 0.f, 0.f};
        f32x4 acc[2][4];
#pragma unroll
        for (int a = 0; a < 2; ++a)
#pragma unroll
            for (int c = 0; c < 4; ++c) acc[a][c] = zero;
        float a2 = 0.f;

        const float* arow = A + (size_t)(i0 + w * 32 + l15) * N + q * 8;
        for (int ch = 0; ch < 8; ++ch) {
            int jb = k0 + ch * 32;
            float4 xa0 = *(const float4*)(arow + jb);
            float4 xa1 = *(const float4*)(arow + jb + 4);
            float4 xb0 = *(const float4*)(arow + (size_t)16 * N + jb);
            float4 xb1 = *(const float4*)(arow + (size_t)16 * N + jb + 4);
            bf16x8 bfr[4];
#pragma unroll
            for (int tb = 0; tb < 4; ++tb)
                bfr[tb] = *(const bf16x8*)(V2b + (size_t)(tb * 16 + l15) * N + jb + q * 8);
            a2 += xa0.x * xa0.x + xa0.y * xa0.y + xa0.z * xa0.z + xa0.w * xa0.w;
            a2 += xa1.x * xa1.x + xa1.y * xa1.y + xa1.z * xa1.z + xa1.w * xa1.w;
            a2 += xb0.x * xb0.x + xb0.y * xb0.y + xb0.z * xb0.z + xb0.w * xb0.w;
            a2 += xb1.x * xb1.x + xb1.y * xb1.y + xb1.z * xb1.z + xb1.w * xb1.w;
            bf16x8 af0 = {(bf16)xa0.x, (bf16)xa0.y, (bf16)xa0.z, (bf16)xa0.w,
                          (bf16)xa1.x, (bf16)xa1.y, (bf16)xa1.z, (bf16)xa1.w};
            bf16x8 af1 = {(bf16)xb0.x, (bf16)xb0.y, (bf16)xb0.z, (bf16)xb0.w,
                          (bf16)xb1.x, (bf16)xb1.y, (bf16)xb1.z, (bf16)xb1.w};
#pragma unroll
            for (int tb = 0; tb < 4; ++tb) {
                acc[0][tb] = __builtin_amdgcn_mfma_f32_16x16x32_bf16(af0, bfr[tb], acc[0][tb], 0, 0, 0);
                acc[1][tb] = __builtin_amdgcn_mfma_f32_16x16x32_bf16(af1, bfr[tb], acc[1][tb], 0, 0, 0);
            }
        }
        float cr = 0.f;
#pragma unroll
        for (int ta = 0; ta < 2; ++ta)
#pragma unroll
            for (int v = 0; v < 4; ++v) {
                int i = i0 + w * 32 + ta * 16 + q * 4 + v;
                const float* wrow = W + (size_t)i * S2 + l15;
#pragma unroll
                for (int tb = 0; tb < 4; ++tb)
                    cr += wrow[tb * 16] * acc[ta][tb][v];
            }
        for (int off = 32; off; off >>= 1) {
            cr += __shfl_down(cr, off, 64);
            a2 += __shfl_down(a2, off, 64);
        }
        if (lane == 0) { reds[w] = a2; redc[w] = cr; }
        __syncthreads();
        if (tid == 0) {
            atomicAdd(lacc + 0, (double)(reds[0] + reds[1] + reds[2] + reds[3]));
            atomicAdd(lacc + 2, (double)(redc[0] + redc[1] + redc[2] + redc[3]));
        }
        return;
    }

    if (bid >= 1424) {
        // ---- gram pairs, upper triangle: one wave per (k<=l) ----
        double* gred = (double*)As;
        int p = (bid - 1424) * 4 + w;
        int kk = (int)((129.0 - sqrt(16641.0 - 8.0 * (double)p)) * 0.5);
        while ((kk + 1) * (129 - (kk + 1)) / 2 <= p) ++kk;
        while (kk * (129 - kk) / 2 > p) --kk;
        int ll = kk + (p - kk * (129 - kk) / 2);
        const float* wk = Wt + (size_t)kk * N;
        const float* wl = Wt + (size_t)ll * N;
        const float* vk = V2 + (size_t)kk * N;
        const float* vl = V2 + (size_t)ll * N;
        float s1 = 0.f, s2 = 0.f;
        for (int it = 0; it < 16; ++it) {
            int j = it * 256 + lane * 4;
            float4 a1 = *(const float4*)(wk + j);
            float4 b1 = *(const float4*)(wl + j);
            float4 a2v = *(const float4*)(vk + j);
            float4 b2v = *(const float4*)(vl + j);
            s1 += a1.x * b1.x + a1.y * b1.y + a1.z * b1.z + a1.w * b1.w;
            s2 += a2v.x * b2v.x + a2v.y * b2v.y + a2v.z * b2v.z + a2v.w * b2v.w;
        }
        for (int off = 32; off; off >>= 1) {
            s1 += __shfl_down(s1, off, 64);
            s2 += __shfl_down(s2, off, 64);
        }
        if (lane == 0) gred[w] = (double)s1 * (double)s2 * ((kk == ll) ? 1.0 : 2.0);
        __syncthreads();
        if (tid == 0)
            pairsum[bid - 1424] = gred[0] + gred[1] + gred[2] + gred[3];
        return;
    }

    // ---- refl_sim upper-triangle tile (bid < 528) ----
    int p = bid;
    int ti = (int)((65.0 - sqrt(4225.0 - 8.0 * (double)p)) * 0.5);
    while ((ti + 1) * (65 - (ti + 1)) / 2 <= p) ++ti;
    while (ti * (65 - ti) / 2 > p) --ti;
    int tj = ti + (p - ti * (65 - ti) / 2);
    int i0 = ti * 128, j0 = tj * 128;
    bool diag = (ti == tj);

    int wm = (w >> 1) * 64, wn = (w & 1) * 64;
    int q = lane >> 4, l15 = lane & 15;
    if (tid < 128) { rs_l[tid] = 0.f; ps_l[tid] = 0.f; rs_c[tid] = 0.f; ps_c[tid] = 0.f; }

    f32x4 zero = {0.f, 0.f, 0.f, 0.f};
    f32x4 d[4][4];
#pragma unroll
    for (int a = 0; a < 4; ++a)
#pragma unroll
        for (int b = 0; b < 4; ++b) d[a][b] = zero;

    for (int k0 = 0; k0 < S0; k0 += 64) {
        __syncthreads();
#pragma unroll
        for (int t = 0; t < 4; ++t) {
            int idx = tid + 256 * t;
            int r = idx >> 3, c = idx & 7;
            uint4 va = *(const uint4*)(hnb + (i0 + r) * S0 + k0 + c * 8);
            uint4 vb = *(const uint4*)(hnb + (j0 + r) * S0 + k0 + c * 8);
            *(uint4*)(As + r * LDK + c * 8) = va;
            *(uint4*)(Bs + r * LDK + c * 8) = vb;
        }
        __syncthreads();
#pragma unroll
        for (int kk = 0; kk < 64; kk += 32) {
            bf16x8 af[4], bfr[4];
#pragma unroll
            for (int ta = 0; ta < 4; ++ta)
                af[ta] = *(const bf16x8*)(As + (wm + ta * 16 + l15) * LDK + kk + q * 8);
#pragma unroll
            for (int tb = 0; tb < 4; ++tb)
                bfr[tb] = *(const bf16x8*)(Bs + (wn + tb * 16 + l15) * LDK + kk + q * 8);
#pragma unroll
            for (int ta = 0; ta < 4; ++ta)
#pragma unroll
                for (int tb = 0; tb < 4; ++tb)
                    d[ta][tb] = __builtin_amdgcn_mfma_f32_16x16x32_bf16(af[ta], bfr[tb], d[ta][tb], 0, 0, 0);
        }
    }
    __syncthreads();
    u64* mwords  = (u64*)As;   // mask rows i0.., column stripe of j0
    u64* mwordsT = (u64*)Bs;   // mask rows j0.., column stripe of i0 (for transpose part)
    int stripe  = j0 >> 8, half  = (j0 >> 7) & 1;
    int stripei = i0 >> 8, halfi = (i0 >> 7) & 1;
    for (int t = tid; t < 512; t += 256) {
        int li = t >> 2, u = t & 3;
        mwords[t] = mask[(size_t)(i0 + li) * 64 + stripe * 4 + u];
        if (!diag)
            mwordsT[t] = mask[(size_t)(j0 + li) * 64 + stripei * 4 + u];
    }
    __syncthreads();
    int bitbase = half * 32 + (wn >> 2) + (l15 >> 2);
    int uoff = l15 & 3;
    float cs[4] = {0.f, 0.f, 0.f, 0.f};
    float csp[4] = {0.f, 0.f, 0.f, 0.f};
#pragma unroll
    for (int ta = 0; ta < 4; ++ta)
#pragma unroll
        for (int v = 0; v < 4; ++v) {
            int li = wm + ta * 16 + q * 4 + v;
            u64 word = mwords[li * 4 + uoff];
            int bitT = halfi * 32 + (wm >> 2) + ta * 4 + q;   // (ri>>2)&63, no wrap
            float rs = 0.f, ps = 0.f;
#pragma unroll
            for (int tb = 0; tb < 4; ++tb) {
                float s = __expf(2.f * d[ta][tb][v]);
                rs += s;
                ps += ((word >> (bitbase + tb * 4)) & 1ULL) ? s : 0.f;
                cs[tb] += s;
                if (!diag) {
                    u64 wt = mwordsT[(wn + tb * 16 + l15) * 4 + v];
                    csp[tb] += ((wt >> bitT) & 1ULL) ? s : 0.f;
                }
            }
#pragma unroll
            for (int m = 1; m < 16; m <<= 1) {
                rs += __shfl_xor(rs, m, 64);
                ps += __shfl_xor(ps, m, 64);
            }
            if (l15 == 0) {
                atomicAdd(&rs_l[li], rs);
                atomicAdd(&ps_l[li], ps);
            }
        }
    if (!diag) {
        // column (transposed-row) sums: reduce over q (lane bits 4,5)
#pragma unroll
        for (int tb = 0; tb < 4; ++tb) {
            float c1 = cs[tb], c2 = csp[tb];
            c1 += __shfl_xor(c1, 16, 64);
            c1 += __shfl_xor(c1, 32, 64);
            c2 += __shfl_xor(c2, 16, 64);
            c2 += __shfl_xor(c2, 32, 64);
            if (lane < 16) {
                atomicAdd(&rs_c[wn + tb * 16 + l15], c1);
                atomicAdd(&ps_c[wn + tb * 16 + l15], c2);
            }
        }
    }
    __syncthreads();
    if (tid < 128) {
        atomicAdd(&rowsum[i0 + tid], rs_l[tid]);
        atomicAdd(&pos4[i0 + tid], ps_l[tid]);
        if (!diag) {
            atomicAdd(&rowsum[j0 + tid], rs_c[tid]);
            atomicAdd(&pos4[j0 + tid], ps_c[tid]);
        }
    }
}

// ---------------- finalize ----------------

__global__ __launch_bounds__(256) void k_final(const float* __restrict__ rowsum,
                                               const float* __restrict__ pos2,
                                               const float* __restrict__ pos3,
                                               const float* __restrict__ pos4,
                                               const double* __restrict__ lacc,
                                               const double* __restrict__ pairsum,
                                               const float* __restrict__ ls5,
                                               float* __restrict__ out) {
    __shared__ double red[5][4];
    int tid = threadIdx.x;
    double l2 = 0, l3 = 0, l4 = 0, sp = 0, l5 = 0;
    for (int i = tid; i < N; i += 256) {
        double rs = (double)rowsum[i];
        float p2 = pos2[i], p3 = pos3[i], p4 = pos4[i];
        if (p2 > 0.f) l2 -= log((double)p2 / rs);
        if (p3 > 0.f) l3 -= log((double)p3 / rs);
        if (p4 > 0.f) l4 -= log((double)p4 / rs);
    }
    for (int i = tid; i < 520; i += 256) sp += pairsum[i];
    for (int i = tid; i < 577; i += 256) l5 += (double)ls5[i];
    int lane = tid & 63, wave = tid >> 6;
    for (int off = 32; off; off >>= 1) {
        l2 += __shfl_down(l2, off, 64);
        l3 += __shfl_down(l3, off, 64);
        l4 += __shfl_down(l4, off, 64);
        sp += __shfl_down(sp, off, 64);
        l5 += __shfl_down(l5, off, 64);
    }
    if (lane == 0) { red[0][wave] = l2; red[1][wave] = l3; red[2][wave] = l4; red[3][wave] = sp; red[4][wave] = l5; }
    __syncthreads();
    if (tid == 0) {
        double L2 = 0, L3 = 0, L4 = 0, SP = 0, L5 = 0;
        for (int w = 0; w < 4; ++w) {
            L2 += red[0][w]; L3 += red[1][w]; L4 += red[2][w]; SP += red[3][w]; L5 += red[4][w];
        }
        L2 /= N; L3 /= N; L4 /= N;
        double L1 = lacc[0] - 2.0 * lacc[2] + SP;   // sumA2 - 2*cross + sumP2
        double total = L1 + 0.1 * (L2 + L3 + L4) + L5;
        out[0] = (float)total;
        out[1] = (float)L1;
        out[2] = (float)L2;
        out[3] = (float)L3;
        out[4] = (float)L4;
        out[5] = (float)L5;
    }
}

extern "C" void kernel_launch(void* const* d_in, const int* in_sizes, int n_in,
                              void* d_out, int out_size, void* d_ws, size_t ws_size,
                              hipStream_t stream) {
    const float* A     = (const float*)d_in[0];
    const float* U0    = (const float*)d_in[1];
    const float* U1    = (const float*)d_in[2];
    const float* U2    = (const float*)d_in[3];
    const float* V2    = (const float*)d_in[4];
    const float* fc1_w = (const float*)d_in[5];
    const float* fc1_b = (const float*)d_in[6];
    const float* fc2_w = (const float*)d_in[7];
    const float* fc2_b = (const float*)d_in[8];
    const float* sim   = (const float*)d_in[9];
    const int* cIdx    = (const int*)d_in[10];
    const int* nIdx    = (const int*)d_in[11];

    float* ws = (float*)d_ws;
    float* rowsum = ws;
    float* pos2 = ws + N;
    float* pos3 = ws + 2 * N;
    float* pos4 = ws + 3 * N;
    double* lacc = (double*)(ws + 4 * N);            // 4 doubles: sumA2, (unused), cross, (unused)
    double* pairsum = lacc + 4;                      // 1024 doubles (520 used)
    u64* mask = (u64*)(pairsum + 1024);              // N*64 words = 2 MB
    bf16* hnb = (bf16*)(mask + (size_t)N * 64);      // 2 MB
    float* W  = (float*)(hnb + (size_t)N * S0);      // N*S2 fp32 = 1 MB
    float* Wt = W + (size_t)N * S2;                  // S2*N fp32 = 1 MB
    bf16* V2b = (bf16*)(Wt + (size_t)S2 * N);        // 0.5 MB
    float* ls5 = (float*)(V2b + (size_t)S2 * N);     // 577 floats

    k_prep<<<3137, 128, 0, stream>>>(U0, U1, U2, V2, fc1_w, fc1_b, fc2_w, fc2_b,
                                     W, Wt, V2b, hnb, ws, ls5, sim, mask);
    k_work<<<1944, 256, 0, stream>>>(hnb, mask, rowsum, pos4, cIdx, nIdx,
                                     pos2, pos3, V2, A, V2b, W, Wt,
                                     lacc, pairsum);
    k_final<<<1, 256, 0, stream>>>(rowsum, pos2, pos3, pos4, lacc, pairsum, ls5,
                                   (float*)d_out);
}

// Round 14
// 254.217 us; speedup vs baseline: 1.1034x; 1.0045x over previous
//
#include <hip/hip_runtime.h>
#include <math.h>
#include <stdint.h>

#define N 4096
#define S0 256
#define S1 128
#define S2 64
#define LDKB 36   // sim-tile LDS row stride in bf16 for K=32 stage (72 B): conflict-free b128

typedef __bf16 bf16;
typedef __attribute__((ext_vector_type(8))) __bf16 bf16x8;
typedef __attribute__((ext_vector_type(4))) __bf16 bf16x4;
typedef __attribute__((ext_vector_type(4))) float f32x4;
typedef unsigned long long u64;

// ---------------- k_prep (R4-proven): chains + V2b + zero + bitmask ----------------
// blocks [0,512):     chain1: W/Wt = (U0@U1)@U2 fp32; U0 negsq -> ls5[bid]
// blocks [512,1024):  chain2: hnb = l2norm(elu(V2^T@fc1^T+b1)@fc2^T+b2)
// blocks [1024,1088): V2b = bf16(V2); V2 negsq -> ls5[512+nb]
// block 1088:         zero accumulators; U1+U2 negsq -> ls5[576]
// blocks [1089,3137): sim>0.9 ballot bitmask, 2 rows/block

__global__ __launch_bounds__(128) void k_prep(const float* __restrict__ U0,
                                              const float* __restrict__ U1,
                                              const float* __restrict__ U2,
                                              const float* __restrict__ V2,
                                              const float* __restrict__ fc1_w,
                                              const float* __restrict__ fc1_b,
                                              const float* __restrict__ fc2_w,
                                              const float* __restrict__ fc2_b,
                                              float* __restrict__ W,
                                              float* __restrict__ Wt,
                                              bf16* __restrict__ V2b,
                                              bf16* __restrict__ hnb,
                                              float* __restrict__ accz,
                                              float* __restrict__ ls5,
                                              const float* __restrict__ sim,
                                              u64* __restrict__ mask) {
    __shared__ __align__(16) char pb[12416];
    int bid = blockIdx.x;
    int tid = threadIdx.x;
    int lane = tid & 63, wv = tid >> 6;

    if (bid < 512) {
        // ---- chain1: 8 rows, 128 threads ----
        float (*u0s)[S0]      = (float(*)[S0])pb;                    // 8192 B (dead after step1)
        float (*ts)[S1 + 4]   = (float(*)[S1 + 4])(pb + 8192);       // 4224 B
        int i0 = bid * 8;
        float ns = 0.f;

        for (int t = tid; t < 8 * S0; t += 128) {
            float x = U0[(i0 + (t >> 8)) * S0 + (t & 255)];
            u0s[t >> 8][t & 255] = x;
            if (x < 0.f) ns += x * x;
        }
        __syncthreads();
        {
            int j = tid;
            float acc[8] = {};
#pragma unroll 8
            for (int k = 0; k < S0; ++k) {
                float u1 = U1[k * S1 + j];
#pragma unroll
                for (int r = 0; r < 8; ++r) acc[r] += u0s[r][k] * u1;
            }
            for (int r = 0; r < 8; ++r) ts[r][j] = acc[r];
        }
        __syncthreads();
        {
            int j = tid & 63, h = tid >> 6;
            float acc2[4] = {};
#pragma unroll 8
            for (int k = 0; k < S1; ++k) {
                float u2 = U2[k * S2 + j];
#pragma unroll
                for (int r = 0; r < 4; ++r) acc2[r] += ts[h * 4 + r][k] * u2;
            }
            for (int r = 0; r < 4; ++r) {
                int i = i0 + h * 4 + r;
                W[i * S2 + j] = acc2[r];
                Wt[(size_t)j * N + i] = acc2[r];
            }
        }
        // U0 negsq partial
        {
            for (int off = 32; off; off >>= 1) ns += __shfl_down(ns, off, 64);
            __syncthreads();
            float* nsr = (float*)pb;
            if (lane == 0) nsr[wv] = ns;
            __syncthreads();
            if (tid == 0) ls5[bid] = nsr[0] + nsr[1];
        }
    } else if (bid < 1024) {
        // ---- chain2: 8 rows, 128 threads ----
        float (*vs)[S2]       = (float(*)[S2])pb;                    // 2048 B
        float (*hs)[S1 + 4]   = (float(*)[S1 + 4])(pb + 2048);       // 4224 B
        float (*red)[8]       = (float(*)[8])(pb + 6272);            // 64 B
        float *norms          = (float*)(pb + 6336);                 // 32 B
        int i0 = (bid - 512) * 8;

        for (int t = tid; t < 8 * S2; t += 128) {
            int r = t & 7, k = t >> 3;
            vs[r][k] = V2[k * N + i0 + r];
        }
        __syncthreads();
        {
            int j = tid;
            float b = fc1_b[j];
            float acc[8];
#pragma unroll
            for (int r = 0; r < 8; ++r) acc[r] = b;
#pragma unroll 4
            for (int kk = 0; kk < S2; kk += 4) {
                float4 w4 = *(const float4*)(fc1_w + j * S2 + kk);
#pragma unroll
                for (int r = 0; r < 8; ++r) {
                    float4 v4 = *(const float4*)(&vs[r][kk]);
                    acc[r] += v4.x * w4.x + v4.y * w4.y + v4.z * w4.z + v4.w * w4.w;
                }
            }
            for (int r = 0; r < 8; ++r) {
                float x = acc[r];
                hs[r][j] = x > 0.f ? x : (expf(x) - 1.f);
            }
        }
        __syncthreads();
        {
            int j = tid;
            float b0 = fc2_b[j], b1 = fc2_b[j + 128];
            float a0[8], a1[8];
#pragma unroll
            for (int r = 0; r < 8; ++r) { a0[r] = b0; a1[r] = b1; }
#pragma unroll 4
            for (int kk = 0; kk < S1; kk += 4) {
                float4 w0 = *(const float4*)(fc2_w + j * S1 + kk);
                float4 w1 = *(const float4*)(fc2_w + (j + 128) * S1 + kk);
#pragma unroll
                for (int r = 0; r < 8; ++r) {
                    float4 h4 = *(const float4*)(&hs[r][kk]);
                    a0[r] += h4.x * w0.x + h4.y * w0.y + h4.z * w0.z + h4.w * w0.w;
                    a1[r] += h4.x * w1.x + h4.y * w1.y + h4.z * w1.z + h4.w * w1.w;
                }
            }
#pragma unroll
            for (int r = 0; r < 8; ++r) {
                float v = a0[r] * a0[r] + a1[r] * a1[r];
                for (int off = 32; off; off >>= 1) v += __shfl_down(v, off, 64);
                if (lane == 0) red[wv][r] = v;
            }
            __syncthreads();
            if (tid < 8) norms[tid] = fmaxf(sqrtf(red[0][tid] + red[1][tid]), 1e-12f);
            __syncthreads();
            for (int r = 0; r < 8; ++r) {
                float inv = 1.f / norms[r];
                hnb[(i0 + r) * S0 + j] = (bf16)(a0[r] * inv);
                hnb[(i0 + r) * S0 + j + 128] = (bf16)(a1[r] * inv);
            }
        }
    } else if (bid < 1088) {
        // ---- V2 -> bf16 + V2 negsq ----
        int nb = bid - 1024;
        float ns = 0.f;
#pragma unroll
        for (int it = 0; it < 8; ++it) {
            int fi = nb * 1024 + it * 128 + tid;
            float4 x = *(const float4*)(V2 + (size_t)fi * 4);
            bf16x4 v = {(bf16)x.x, (bf16)x.y, (bf16)x.z, (bf16)x.w};
            *(bf16x4*)(V2b + (size_t)fi * 4) = v;
            if (x.x < 0.f) ns += x.x * x.x;
            if (x.y < 0.f) ns += x.y * x.y;
            if (x.z < 0.f) ns += x.z * x.z;
            if (x.w < 0.f) ns += x.w * x.w;
        }
        for (int off = 32; off; off >>= 1) ns += __shfl_down(ns, off, 64);
        float* nsr = (float*)pb;
        if (lane == 0) nsr[wv] = ns;
        __syncthreads();
        if (tid == 0) ls5[512 + nb] = nsr[0] + nsr[1];
    } else if (bid == 1088) {
        // ---- zero accumulators + U1/U2 negsq ----
        float ns = 0.f;
        for (int t = tid; t < (S0 * S1 + S1 * S2) / 4; t += 128) {
            float4 x = (t < S0 * S1 / 4) ? ((const float4*)U1)[t]
                                         : ((const float4*)U2)[t - S0 * S1 / 4];
            if (x.x < 0.f) ns += x.x * x.x;
            if (x.y < 0.f) ns += x.y * x.y;
            if (x.z < 0.f) ns += x.z * x.z;
            if (x.w < 0.f) ns += x.w * x.w;
        }
        for (int t = tid; t < 4 * N + 8; t += 128) accz[t] = 0.f;
        for (int off = 32; off; off >>= 1) ns += __shfl_down(ns, off, 64);
        float* nsr = (float*)pb;
        if (lane == 0) nsr[wv] = ns;
        __syncthreads();
        if (tid == 0) ls5[576] = nsr[0] + nsr[1];
    } else {
        // ---- sim>0.9 ballot bitmask, 2 rows/block ----
        int row = (bid - 1089) * 2 + wv;
        const float* base = sim + (size_t)row * N + lane * 4;
#pragma unroll
        for (int half = 0; half < 2; ++half) {
            float4 x[8];
#pragma unroll
            for (int it = 0; it < 8; ++it)
                x[it] = *(const float4*)(base + (half * 8 + it) * 256);
#pragma unroll
            for (int it = 0; it < 8; ++it) {
                u64 b0 = __ballot(x[it].x > 0.9f);
                u64 b1 = __ballot(x[it].y > 0.9f);
                u64 b2 = __ballot(x[it].z > 0.9f);
                u64 b3 = __ballot(x[it].w > 0.9f);
                if (lane < 4) {
                    u64 v = (lane == 0) ? b0 : (lane == 1) ? b1 : (lane == 2) ? b2 : b3;
                    mask[(size_t)row * 64 + (half * 8 + it) * 4 + lane] = v;
                }
            }
        }
    }
}

// ---------------- k_work v4: K=32 sim stages (20.5 KB LDS -> ~6 blocks/CU) ----------------
// blocks [0,528):     refl_sim upper-triangle tile (ti<=tj); off-diag tiles also emit the
//                     transposed contributions (column sums + transposed mask bits)
// blocks [528,912):   pos_idx tail (pos2/pos3)
// blocks [912,1424):  loss1G MFMA (verbatim)
// blocks [1424,1944): gram pairs upper triangle (verbatim)

__global__ __launch_bounds__(256) void k_work(const bf16* __restrict__ hnb,
                                              const u64* __restrict__ mask,
                                              float* __restrict__ rowsum,
                                              float* __restrict__ pos4,
                                              const int* __restrict__ cIdx,
                                              const int* __restrict__ nIdx,
                                              float* __restrict__ pos2,
                                              float* __restrict__ pos3,
                                              const float* __restrict__ V2,
                                              const float* __restrict__ A,
                                              const bf16* __restrict__ V2b,
                                              const float* __restrict__ W,
                                              const float* __restrict__ Wt,
                                              double* __restrict__ lacc,
                                              double* __restrict__ pairsum) {
    __shared__ __align__(16) bf16 As[128 * LDKB];    // 9216 B; aliased as mwords after MFMA
    __shared__ __align__(16) bf16 Bs[128 * LDKB];    // 9216 B; aliased as mwordsT after MFMA
    __shared__ float rs_l[128], ps_l[128];
    __shared__ float rs_c[128], ps_c[128];
    int bid = blockIdx.x;
    int tid = threadIdx.x;
    int lane = tid & 63, w = tid >> 6;

    if (bid >= 528 && bid < 912) {
        // ---- pos_idx tail ----
        int g = (bid - 528) * 256 + tid;
        if (g >= N * 24) return;
        int i = g / 24, s = g % 24;
        const int* idx;
        int kk;
        float* dst;
        if (s < 8) { idx = cIdx + i * 8; kk = s; dst = pos2; }
        else       { idx = nIdx + i * 16; kk = s - 8; dst = pos3; }
        int t = idx[kk];
        for (int k = 0; k < kk; ++k)
            if (idx[k] == t) return;  // mask is a set: duplicates count once
        const bf16* a = hnb + i * S0;
        const bf16* b = hnb + t * S0;
        float dsum = 0.f;
        for (int k = 0; k < S0; k += 8) {
            bf16x8 av = *(const bf16x8*)(a + k);
            bf16x8 bv = *(const bf16x8*)(b + k);
#pragma unroll
            for (int u = 0; u < 8; ++u) dsum += (float)av[u] * (float)bv[u];
        }
        atomicAdd(dst + i, __expf(2.f * dsum));
        return;
    }

    if (bid >= 912 && bid < 1424) {
        // ---- loss1G: direct-load MFMA ----
        float* reds = (float*)As;
        float* redc = reds + 4;
        int b = bid - 912;
        int split = b >> 5, rb = b & 31;
        int i0 = rb * 128, k0 = split * 256;
        int q = lane >> 4, l15 = lane & 15;

        f32x4 zero = {0.f, 0.f, 0.f, 0.f};
        f32x4 acc[2][4];
#pragma unroll
        for (int a = 0; a < 2; ++a)
#pragma unroll
            for (int c = 0; c < 4; ++c) acc[a][c] = zero;
        float a2 = 0.f;

        const float* arow = A + (size_t)(i0 + w * 32 + l15) * N + q * 8;
        for (int ch = 0; ch < 8; ++ch) {
            int jb = k0 + ch * 32;
            float4 xa0 = *(const float4*)(arow + jb);
            float4 xa1 = *(const float4*)(arow + jb + 4);
            float4 xb0 = *(const float4*)(arow + (size_t)16 * N + jb);
            float4 xb1 = *(const float4*)(arow + (size_t)16 * N + jb + 4);
            bf16x8 bfr[4];
#pragma unroll
            for (int tb = 0; tb < 4; ++tb)
                bfr[tb] = *(const bf16x8*)(V2b + (size_t)(tb * 16 + l15) * N + jb + q * 8);
            a2 += xa0.x * xa0.x + xa0.y * xa0.y + xa0.z * xa0.z + xa0.w * xa0.w;
            a2 += xa1.x * xa1.x + xa1.y * xa1.y + xa1.z * xa1.z + xa1.w * xa1.w;
            a2 += xb0.x * xb0.x + xb0.y * xb0.y + xb0.z * xb0.z + xb0.w * xb0.w;
            a2 += xb1.x * xb1.x + xb1.y * xb1.y + xb1.z * xb1.z + xb1.w * xb1.w;
            bf16x8 af0 = {(bf16)xa0.x, (bf16)xa0.y, (bf16)xa0.z, (bf16)xa0.w,
                          (bf16)xa1.x, (bf16)xa1.y, (bf16)xa1.z, (bf16)xa1.w};
            bf16x8 af1 = {(bf16)xb0.x, (bf16)xb0.y, (bf16)xb0.z, (bf16)xb0.w,
                          (bf16)xb1.x, (bf16)xb1.y, (bf16)xb1.z, (bf16)xb1.w};
#pragma unroll
            for (int tb = 0; tb < 4; ++tb) {
                acc[0][tb] = __builtin_amdgcn_mfma_f32_16x16x32_bf16(af0, bfr[tb], acc[0][tb], 0, 0, 0);
                acc[1][tb] = __builtin_amdgcn_mfma_f32_16x16x32_bf16(af1, bfr[tb], acc[1][tb], 0, 0, 0);
            }
        }
        float cr = 0.f;
#pragma unroll
        for (int ta = 0; ta < 2; ++ta)
#pragma unroll
            for (int v = 0; v < 4; ++v) {
                int i = i0 + w * 32 + ta * 16 + q * 4 + v;
                const float* wrow = W + (size_t)i * S2 + l15;
#pragma unroll
                for (int tb = 0; tb < 4; ++tb)
                    cr += wrow[tb * 16] * acc[ta][tb][v];
            }
        for (int off = 32; off; off >>= 1) {
            cr += __shfl_down(cr, off, 64);
            a2 += __shfl_down(a2, off, 64);
        }
        if (lane == 0) { reds[w] = a2; redc[w] = cr; }
        __syncthreads();
        if (tid == 0) {
            atomicAdd(lacc + 0, (double)(reds[0] + reds[1] + reds[2] + reds[3]));
            atomicAdd(lacc + 2, (double)(redc[0] + redc[1] + redc[2] + redc[3]));
        }
        return;
    }

    if (bid >= 1424) {
        // ---- gram pairs, upper triangle: one wave per (k<=l) ----
        double* gred = (double*)As;
        int p = (bid - 1424) * 4 + w;
        int kk = (int)((129.0 - sqrt(16641.0 - 8.0 * (double)p)) * 0.5);
        while ((kk + 1) * (129 - (kk + 1)) / 2 <= p) ++kk;
        while (kk * (129 - kk) / 2 > p) --kk;
        int ll = kk + (p - kk * (129 - kk) / 2);
        const float* wk = Wt + (size_t)kk * N;
        const float* wl = Wt + (size_t)ll * N;
        const float* vk = V2 + (size_t)kk * N;
        const float* vl = V2 + (size_t)ll * N;
        float s1 = 0.f, s2 = 0.f;
        for (int it = 0; it < 16; ++it) {
            int j = it * 256 + lane * 4;
            float4 a1 = *(const float4*)(wk + j);
            float4 b1 = *(const float4*)(wl + j);
            float4 a2v = *(const float4*)(vk + j);
            float4 b2v = *(const float4*)(vl + j);
            s1 += a1.x * b1.x + a1.y * b1.y + a1.z * b1.z + a1.w * b1.w;
            s2 += a2v.x * b2v.x + a2v.y * b2v.y + a2v.z * b2v.z + a2v.w * b2v.w;
        }
        for (int off = 32; off; off >>= 1) {
            s1 += __shfl_down(s1, off, 64);
            s2 += __shfl_down(s2, off, 64);
        }
        if (lane == 0) gred[w] = (double)s1 * (double)s2 * ((kk == ll) ? 1.0 : 2.0);
        __syncthreads();
        if (tid == 0)
            pairsum[bid - 1424] = gred[0] + gred[1] + gred[2] + gred[3];
        return;
    }

    // ---- refl_sim upper-triangle tile (bid < 528), K=32 stages ----
    int p = bid;
    int ti = (int)((65.0 - sqrt(4225.0 - 8.0 * (double)p)) * 0.5);
    while ((ti + 1) * (65 - (ti + 1)) / 2 <= p) ++ti;
    while (ti * (65 - ti) / 2 > p) --ti;
    int tj = ti + (p - ti * (65 - ti) / 2);
    int i0 = ti * 128, j0 = tj * 128;
    bool diag = (ti == tj);

    int wm = (w >> 1) * 64, wn = (w & 1) * 64;
    int q = lane >> 4, l15 = lane & 15;
    if (tid < 128) { rs_l[tid] = 0.f; ps_l[tid] = 0.f; rs_c[tid] = 0.f; ps_c[tid] = 0.f; }

    f32x4 zero = {0.f, 0.f, 0.f, 0.f};
    f32x4 d[4][4];
#pragma unroll
    for (int a = 0; a < 4; ++a)
#pragma unroll
        for (int b = 0; b < 4; ++b) d[a][b] = zero;

    for (int k0 = 0; k0 < S0; k0 += 32) {
        __syncthreads();
#pragma unroll
        for (int t = 0; t < 2; ++t) {
            int idx = tid + 256 * t;           // 0..511
            int r = idx >> 2, c = idx & 3;
            uint4 va = *(const uint4*)(hnb + (i0 + r) * S0 + k0 + c * 8);
            uint4 vb = *(const uint4*)(hnb + (j0 + r) * S0 + k0 + c * 8);
            *(uint4*)(As + r * LDKB + c * 8) = va;
            *(uint4*)(Bs + r * LDKB + c * 8) = vb;
        }
        __syncthreads();
        bf16x8 af[4], bfr[4];
#pragma unroll
        for (int ta = 0; ta < 4; ++ta)
            af[ta] = *(const bf16x8*)(As + (wm + ta * 16 + l15) * LDKB + q * 8);
#pragma unroll
        for (int tb = 0; tb < 4; ++tb)
            bfr[tb] = *(const bf16x8*)(Bs + (wn + tb * 16 + l15) * LDKB + q * 8);
#pragma unroll
        for (int ta = 0; ta < 4; ++ta)
#pragma unroll
            for (int tb = 0; tb < 4; ++tb)
                d[ta][tb] = __builtin_amdgcn_mfma_f32_16x16x32_bf16(af[ta], bfr[tb], d[ta][tb], 0, 0, 0);
    }
    __syncthreads();
    u64* mwords  = (u64*)As;   // mask rows i0.., column stripe of j0
    u64* mwordsT = (u64*)Bs;   // mask rows j0.., column stripe of i0 (for transpose part)
    int stripe  = j0 >> 8, half  = (j0 >> 7) & 1;
    int stripei = i0 >> 8, halfi = (i0 >> 7) & 1;
    for (int t = tid; t < 512; t += 256) {
        int li = t >> 2, u = t & 3;
        mwords[t] = mask[(size_t)(i0 + li) * 64 + stripe * 4 + u];
        if (!diag)
            mwordsT[t] = mask[(size_t)(j0 + li) * 64 + stripei * 4 + u];
    }
    __syncthreads();
    int bitbase = half * 32 + (wn >> 2) + (l15 >> 2);
    int uoff = l15 & 3;
    float cs[4] = {0.f, 0.f, 0.f, 0.f};
    float csp[4] = {0.f, 0.f, 0.f, 0.f};
#pragma unroll
    for (int ta = 0; ta < 4; ++ta)
#pragma unroll
        for (int v = 0; v < 4; ++v) {
            int li = wm + ta * 16 + q * 4 + v;
            u64 word = mwords[li * 4 + uoff];
            int bitT = halfi * 32 + (wm >> 2) + ta * 4 + q;   // (ri>>2)&63, no wrap
            float rs = 0.f, ps = 0.f;
#pragma unroll
            for (int tb = 0; tb < 4; ++tb) {
                float s = __expf(2.f * d[ta][tb][v]);
                rs += s;
                ps += ((word >> (bitbase + tb * 4)) & 1ULL) ? s : 0.f;
                cs[tb] += s;
                if (!diag) {
                    u64 wt = mwordsT[(wn + tb * 16 + l15) * 4 + v];
                    csp[tb] += ((wt >> bitT) & 1ULL) ? s : 0.f;
                }
            }
#pragma unroll
            for (int m = 1; m < 16; m <<= 1) {
                rs += __shfl_xor(rs, m, 64);
                ps += __shfl_xor(ps, m, 64);
            }
            if (l15 == 0) {
                atomicAdd(&rs_l[li], rs);
                atomicAdd(&ps_l[li], ps);
            }
        }
    if (!diag) {
        // column (transposed-row) sums: reduce over q (lane bits 4,5)
#pragma unroll
        for (int tb = 0; tb < 4; ++tb) {
            float c1 = cs[tb], c2 = csp[tb];
            c1 += __shfl_xor(c1, 16, 64);
            c1 += __shfl_xor(c1, 32, 64);
            c2 += __shfl_xor(c2, 16, 64);
            c2 += __shfl_xor(c2, 32, 64);
            if (lane < 16) {
                atomicAdd(&rs_c[wn + tb * 16 + l15], c1);
                atomicAdd(&ps_c[wn + tb * 16 + l15], c2);
            }
        }
    }
    __syncthreads();
    if (tid < 128) {
        atomicAdd(&rowsum[i0 + tid], rs_l[tid]);
        atomicAdd(&pos4[i0 + tid], ps_l[tid]);
        if (!diag) {
            atomicAdd(&rowsum[j0 + tid], rs_c[tid]);
            atomicAdd(&pos4[j0 + tid], ps_c[tid]);
        }
    }
}

// ---------------- finalize ----------------

__global__ __launch_bounds__(256) void k_final(const float* __restrict__ rowsum,
                                               const float* __restrict__ pos2,
                                               const float* __restrict__ pos3,
                                               const float* __restrict__ pos4,
                                               const double* __restrict__ lacc,
                                               const double* __restrict__ pairsum,
                                               const float* __restrict__ ls5,
                                               float* __restrict__ out) {
    __shared__ double red[5][4];
    int tid = threadIdx.x;
    double l2 = 0, l3 = 0, l4 = 0, sp = 0, l5 = 0;
    for (int i = tid; i < N; i += 256) {
        double rs = (double)rowsum[i];
        float p2 = pos2[i], p3 = pos3[i], p4 = pos4[i];
        if (p2 > 0.f) l2 -= log((double)p2 / rs);
        if (p3 > 0.f) l3 -= log((double)p3 / rs);
        if (p4 > 0.f) l4 -= log((double)p4 / rs);
    }
    for (int i = tid; i < 520; i += 256) sp += pairsum[i];
    for (int i = tid; i < 577; i += 256) l5 += (double)ls5[i];
    int lane = tid & 63, wave = tid >> 6;
    for (int off = 32; off; off >>= 1) {
        l2 += __shfl_down(l2, off, 64);
        l3 += __shfl_down(l3, off, 64);
        l4 += __shfl_down(l4, off, 64);
        sp += __shfl_down(sp, off, 64);
        l5 += __shfl_down(l5, off, 64);
    }
    if (lane == 0) { red[0][wave] = l2; red[1][wave] = l3; red[2][wave] = l4; red[3][wave] = sp; red[4][wave] = l5; }
    __syncthreads();
    if (tid == 0) {
        double L2 = 0, L3 = 0, L4 = 0, SP = 0, L5 = 0;
        for (int w = 0; w < 4; ++w) {
            L2 += red[0][w]; L3 += red[1][w]; L4 += red[2][w]; SP += red[3][w]; L5 += red[4][w];
        }
        L2 /= N; L3 /= N; L4 /= N;
        double L1 = lacc[0] - 2.0 * lacc[2] + SP;   // sumA2 - 2*cross + sumP2
        double total = L1 + 0.1 * (L2 + L3 + L4) + L5;
        out[0] = (float)total;
        out[1] = (float)L1;
        out[2] = (float)L2;
        out[3] = (float)L3;
        out[4] = (float)L4;
        out[5] = (float)L5;
    }
}

extern "C" void kernel_launch(void* const* d_in, const int* in_sizes, int n_in,
                              void* d_out, int out_size, void* d_ws, size_t ws_size,
                              hipStream_t stream) {
    const float* A     = (const float*)d_in[0];
    const float* U0    = (const float*)d_in[1];
    const float* U1    = (const float*)d_in[2];
    const float* U2    = (const float*)d_in[3];
    const float* V2    = (const float*)d_in[4];
    const float* fc1_w = (const float*)d_in[5];
    const float* fc1_b = (const float*)d_in[6];
    const float* fc2_w = (const float*)d_in[7];
    const float* fc2_b = (const float*)d_in[8];
    const float* sim   = (const float*)d_in[9];
    const int* cIdx    = (const int*)d_in[10];
    const int* nIdx    = (const int*)d_in[11];

    float* ws = (float*)d_ws;
    float* rowsum = ws;
    float* pos2 = ws + N;
    float* pos3 = ws + 2 * N;
    float* pos4 = ws + 3 * N;
    double* lacc = (double*)(ws + 4 * N);            // 4 doubles: sumA2, (unused), cross, (unused)
    double* pairsum = lacc + 4;                      // 1024 doubles (520 used)
    u64* mask = (u64*)(pairsum + 1024);              // N*64 words = 2 MB
    bf16* hnb = (bf16*)(mask + (size_t)N * 64);      // 2 MB
    float* W  = (float*)(hnb + (size_t)N * S0);      // N*S2 fp32 = 1 MB
    float* Wt = W + (size_t)N * S2;                  // S2*N fp32 = 1 MB
    bf16* V2b = (bf16*)(Wt + (size_t)S2 * N);        // 0.5 MB
    float* ls5 = (float*)(V2b + (size_t)S2 * N);     // 577 floats

    k_prep<<<3137, 128, 0, stream>>>(U0, U1, U2, V2, fc1_w, fc1_b, fc2_w, fc2_b,
                                     W, Wt, V2b, hnb, ws, ls5, sim, mask);
    k_work<<<1944, 256, 0, stream>>>(hnb, mask, rowsum, pos4, cIdx, nIdx,
                                     pos2, pos3, V2, A, V2b, W, Wt,
                                     lacc, pairsum);
    k_final<<<1, 256, 0, stream>>>(rowsum, pos2, pos3, pos4, lacc, pairsum, ls5,
                                   (float*)d_out);
}